// Round 2
// baseline (684.451 us; speedup 1.0000x reference)
//
#include <hip/hip_runtime.h>
#include <hip/hip_bf16.h>
#include <math.h>

#define TT 2048
#define DD 2048
#define EE 8
#define II 2048
#define SOFTCAP 30.0f

typedef __attribute__((ext_vector_type(8))) short short8;
typedef __attribute__((ext_vector_type(4))) float f32x4;
typedef unsigned short u16;

__device__ __forceinline__ u16 f2bs(float f) {
    union { __hip_bfloat16 h; u16 u; } cv;
    cv.h = __float2bfloat16(f);
    return cv.u;
}

__device__ __forceinline__ void st_bf4(u16* p, float4 v) {
    unsigned int lo = (unsigned int)f2bs(v.x) | ((unsigned int)f2bs(v.y) << 16);
    unsigned int hi = (unsigned int)f2bs(v.z) | ((unsigned int)f2bs(v.w) << 16);
    *(uint2*)p = make_uint2(lo, hi);
}

__device__ __forceinline__ void gload16(const void* g, void* l) {
    __builtin_amdgcn_global_load_lds(
        (const __attribute__((address_space(1))) unsigned int*)g,
        (__attribute__((address_space(3))) unsigned int*)l,
        16, 0, 0);
}

// ---------------- fp32 -> bf16 bulk convert, all 3 weights in one launch ----
// ORDER MATTERS: w2 first (y==0), w1/w3 last, so the 134 MB gemm_h needs
// (w1b+w3b) is the freshest resident content in the 256 MB Infinity Cache.
__global__ __launch_bounds__(256) void cvt3_kernel(
    const float* __restrict__ w1, const float* __restrict__ w3,
    const float* __restrict__ w2, u16* __restrict__ d1, u16* __restrict__ d3,
    u16* __restrict__ d2, long long n)
{
    const float* s;
    u16* d;
    if (blockIdx.y == 0)      { s = w2; d = d2; }
    else if (blockIdx.y == 1) { s = w1; d = d1; }
    else                      { s = w3; d = d3; }
    long long i = ((long long)blockIdx.x * 256 + threadIdx.x) * 8;
    if (i >= n) return;
    float4 a = *(const float4*)(s + i);
    float4 b = *(const float4*)(s + i + 4);
    st_bf4(d + i, a);
    st_bf4(d + i + 4, b);
}

// ---------------- router: wave per token; also emits x in bf16 --------------
__global__ __launch_bounds__(256) void router2_kernel(
    const float* __restrict__ x, const float* __restrict__ wg,
    int* __restrict__ counts, int* __restrict__ list, float* __restrict__ wlist,
    u16* __restrict__ xb)
{
    const int wid = threadIdx.x >> 6;
    const int lane = threadIdx.x & 63;
    const int t = blockIdx.x * 4 + wid;
    const float* xr = x + (size_t)t * DD;
    float acc[EE];
#pragma unroll
    for (int e = 0; e < EE; ++e) acc[e] = 0.f;
    for (int i = 0; i < DD; i += 256) {
        float4 xv = *(const float4*)(xr + i + lane * 4);
        if (xb) st_bf4(xb + (size_t)t * DD + i + lane * 4, xv);
#pragma unroll
        for (int e = 0; e < EE; ++e) {
            float4 wv = *(const float4*)(wg + (size_t)e * DD + i + lane * 4);
            acc[e] += xv.x * wv.x + xv.y * wv.y + xv.z * wv.z + xv.w * wv.w;
        }
    }
#pragma unroll
    for (int e = 0; e < EE; ++e) {
#pragma unroll
        for (int off = 32; off > 0; off >>= 1)
            acc[e] += __shfl_xor(acc[e], off, 64);
    }
    if (lane == 0) {
        float p[EE];
        float mx = -1e30f;
#pragma unroll
        for (int e = 0; e < EE; ++e) {
            p[e] = SOFTCAP * tanhf(acc[e] / SOFTCAP);
            mx = fmaxf(mx, p[e]);
        }
        float s = 0.f;
#pragma unroll
        for (int e = 0; e < EE; ++e) { p[e] = expf(p[e] - mx); s += p[e]; }
        float inv = 1.f / s;
        int i0 = 0;
#pragma unroll
        for (int e = 1; e < EE; ++e) if (p[e] > p[i0]) i0 = e;
        int i1 = (i0 == 0) ? 1 : 0;
#pragma unroll
        for (int e = 0; e < EE; ++e) if (e != i0 && p[e] > p[i1]) i1 = e;
        int pos0 = atomicAdd(&counts[i0], 1);
        list[i0 * TT + pos0] = t * 2;
        wlist[i0 * TT + pos0] = p[i0] * inv;
        int pos1 = atomicAdd(&counts[i1], 1);
        list[i1 * TT + pos1] = t * 2 + 1;
        wlist[i1 * TT + pos1] = p[i1] * inv;
    }
}

// ======== bf16 fast path =====================================================
// LDS swizzle (both GEMMs): slot (row,s) holds data col s^((row>>1)&3); the
// per-lane GLOBAL source col is pre-swizzled (gload_lds writes linearly), the
// ds_read col applies the same XOR.  Bank conflicts: 0 (verified round 1).
//
// Pipeline (T3/T4 minimum form): 4 LDS buffers, prefetch depth 4, counted
// s_waitcnt vmcnt(12) (3 tiles = 12 loads stay in flight ACROSS barriers),
// raw s_barrier only — __syncthreads would drain vmcnt(0) and kill the
// pipeline (round-1 post-mortem).  Per step j (buffer u = j&3):
//   vmcnt(12)  -> my tile-j loads landed (in-order retirement)
//   s_barrier  -> everyone's tile-j loads landed
//   ds_read tile j -> regs ; lgkmcnt(0)
//   s_barrier  -> everyone done READING buffer u; safe to overwrite
//   STAGE tile j+4 into buffer u ; 16 MFMA on tile j
// sched_barrier(0) fences pin the asm waits (rule: hipcc reorders past
// inline-asm waitcnt otherwise).

#define SB0 __builtin_amdgcn_sched_barrier(0)

// phase A: h = gelu(x@w1^T)*(x@w3^T)*cw ; tile 128M x 64N x 32K, dual-matrix
__global__ __launch_bounds__(256) void gemm_h_bf16(
    const u16* __restrict__ xb, const u16* __restrict__ w1b,
    const u16* __restrict__ w3b, const int* __restrict__ counts,
    const int* __restrict__ list, const float* __restrict__ wlist,
    u16* __restrict__ H)
{
    const int e = blockIdx.z;
    const int cnt = counts[e];
    const int m0 = blockIdx.y * 128;
    if (m0 >= cnt) return;
    const int n0 = blockIdx.x * 64;
    const int tid = threadIdx.x;
    const int lane = tid & 63;
    const int w = tid >> 6;

    __shared__ u16 As[4][128 * 32];
    __shared__ u16 W1s[4][64 * 32];
    __shared__ u16 W3s[4][64 * 32];

    const int colb = ((lane & 3) ^ ((lane >> 3) & 3)) * 8;  // pre-swizzled src col
    const int rsub = lane >> 2;
    const int rA0 = w * 16 + rsub;
    const int rA1 = 64 + rA0;
    const int mA0 = m0 + rA0, mA1 = m0 + rA1;
    const int t0 = (mA0 < cnt) ? (list[e * TT + mA0] >> 1) : 0;
    const int t1 = (mA1 < cnt) ? (list[e * TT + mA1] >> 1) : 0;
    const u16* gA0 = xb + (size_t)t0 * DD + colb;
    const u16* gA1 = xb + (size_t)t1 * DD + colb;
    const int rW = w * 16 + rsub;
    const u16* gW1 = w1b + ((size_t)e * II + n0 + rW) * DD + colb;
    const u16* gW3 = w3b + ((size_t)e * II + n0 + rW) * DD + colb;

    const int wm = w >> 1, wn = w & 1;
    const int lr = lane & 15;
    const int quad = lane >> 4;
    const int qc = (quad ^ ((lr >> 1) & 3)) * 8;  // swizzled read col (u16 units)

    f32x4 accA[4][2], accB[4][2];
#pragma unroll
    for (int mi = 0; mi < 4; ++mi)
#pragma unroll
        for (int ni = 0; ni < 2; ++ni) {
            accA[mi][ni] = (f32x4)0.f;
            accB[mi][ni] = (f32x4)0.f;
        }

#define STAGE_H(u, kk) do { \
    gload16(gA0 + (kk), &As[u][(w * 16) * 32]); \
    gload16(gA1 + (kk), &As[u][(64 + w * 16) * 32]); \
    gload16(gW1 + (kk), &W1s[u][(w * 16) * 32]); \
    gload16(gW3 + (kk), &W3s[u][(w * 16) * 32]); \
} while (0)

#define HSTEP(u, j, VM, DOSTAGE) do { \
    asm volatile("s_waitcnt vmcnt(" #VM ")" ::: "memory"); \
    SB0; \
    __builtin_amdgcn_s_barrier(); \
    SB0; \
    short8 af[4], b1f[2], b3f[2]; \
    _Pragma("unroll") \
    for (int mi = 0; mi < 4; ++mi) \
        af[mi] = *(const short8*)&As[u][(wm * 64 + mi * 16 + lr) * 32 + qc]; \
    _Pragma("unroll") \
    for (int ni = 0; ni < 2; ++ni) { \
        b1f[ni] = *(const short8*)&W1s[u][(wn * 32 + ni * 16 + lr) * 32 + qc]; \
        b3f[ni] = *(const short8*)&W3s[u][(wn * 32 + ni * 16 + lr) * 32 + qc]; \
    } \
    SB0; \
    asm volatile("s_waitcnt lgkmcnt(0)" ::: "memory"); \
    SB0; \
    __builtin_amdgcn_s_barrier(); \
    SB0; \
    if (DOSTAGE) STAGE_H(u, ((j) + 4) * 32); \
    _Pragma("unroll") \
    for (int mi = 0; mi < 4; ++mi) \
        _Pragma("unroll") \
        for (int ni = 0; ni < 2; ++ni) { \
            accA[mi][ni] = __builtin_amdgcn_mfma_f32_16x16x32_bf16(af[mi], b1f[ni], accA[mi][ni], 0, 0, 0); \
            accB[mi][ni] = __builtin_amdgcn_mfma_f32_16x16x32_bf16(af[mi], b3f[ni], accB[mi][ni], 0, 0, 0); \
        } \
} while (0)

    STAGE_H(0, 0);
    STAGE_H(1, 32);
    STAGE_H(2, 64);
    STAGE_H(3, 96);

    for (int g = 0; g < 15; ++g) {
        const int j = g * 4;
        HSTEP(0, j + 0, 12, true);
        HSTEP(1, j + 1, 12, true);
        HSTEP(2, j + 2, 12, true);
        HSTEP(3, j + 3, 12, true);
    }
    HSTEP(0, 60, 12, false);
    HSTEP(1, 61, 8, false);
    HSTEP(2, 62, 4, false);
    HSTEP(3, 63, 0, false);
#undef HSTEP
#undef STAGE_H

#pragma unroll
    for (int mi = 0; mi < 4; ++mi) {
#pragma unroll
        for (int reg = 0; reg < 4; ++reg) {
            int m = m0 + wm * 64 + mi * 16 + quad * 4 + reg;
            if (m < cnt) {
                int entry = list[e * TT + m];
                float cw = wlist[e * TT + m];
                size_t hbase = (size_t)entry * II;
#pragma unroll
                for (int ni = 0; ni < 2; ++ni) {
                    int col = n0 + wn * 32 + ni * 16 + lr;
                    float a = accA[mi][ni][reg];
                    float b = accB[mi][ni][reg];
                    float g2 = 0.5f * a * (1.0f + erff(a * 0.70710678118654752f));
                    H[hbase + col] = f2bs(g2 * b * cw);
                }
            }
        }
    }
}

// phase B: Y[entry] = H[entry] @ w2^T, plain stores (no atomics); 128x128x32
__global__ __launch_bounds__(256) void gemm_y_bf16(
    const u16* __restrict__ H, const u16* __restrict__ w2b,
    const int* __restrict__ counts, const int* __restrict__ list,
    float* __restrict__ Y)
{
    const int e = blockIdx.z;
    const int cnt = counts[e];
    const int m0 = blockIdx.y * 128;
    if (m0 >= cnt) return;
    const int n0 = blockIdx.x * 128;
    const int tid = threadIdx.x;
    const int lane = tid & 63;
    const int w = tid >> 6;

    __shared__ u16 As[4][128 * 32];
    __shared__ u16 Bs[4][128 * 32];

    const int colb = ((lane & 3) ^ ((lane >> 3) & 3)) * 8;
    const int rsub = lane >> 2;
    const int rA0 = w * 16 + rsub;
    const int rA1 = 64 + rA0;
    const int eA0 = (m0 + rA0 < cnt) ? list[e * TT + m0 + rA0] : 0;
    const int eA1 = (m0 + rA1 < cnt) ? list[e * TT + m0 + rA1] : 0;
    const u16* gA0 = H + (size_t)eA0 * II + colb;
    const u16* gA1 = H + (size_t)eA1 * II + colb;
    const u16* gB0 = w2b + ((size_t)e * DD + n0 + rA0) * II + colb;
    const u16* gB1 = w2b + ((size_t)e * DD + n0 + rA1) * II + colb;

    const int wm = w >> 1, wn = w & 1;
    const int lr = lane & 15;
    const int quad = lane >> 4;
    const int qc = (quad ^ ((lr >> 1) & 3)) * 8;

    f32x4 acc[4][4];
#pragma unroll
    for (int mi = 0; mi < 4; ++mi)
#pragma unroll
        for (int ni = 0; ni < 4; ++ni) acc[mi][ni] = (f32x4)0.f;

#define STAGE_Y(u, kk) do { \
    gload16(gA0 + (kk), &As[u][(w * 16) * 32]); \
    gload16(gA1 + (kk), &As[u][(64 + w * 16) * 32]); \
    gload16(gB0 + (kk), &Bs[u][(w * 16) * 32]); \
    gload16(gB1 + (kk), &Bs[u][(64 + w * 16) * 32]); \
} while (0)

#define YSTEP(u, j, VM, DOSTAGE) do { \
    asm volatile("s_waitcnt vmcnt(" #VM ")" ::: "memory"); \
    SB0; \
    __builtin_amdgcn_s_barrier(); \
    SB0; \
    short8 af[4], bf[4]; \
    _Pragma("unroll") \
    for (int mi = 0; mi < 4; ++mi) \
        af[mi] = *(const short8*)&As[u][(wm * 64 + mi * 16 + lr) * 32 + qc]; \
    _Pragma("unroll") \
    for (int ni = 0; ni < 4; ++ni) \
        bf[ni] = *(const short8*)&Bs[u][(wn * 64 + ni * 16 + lr) * 32 + qc]; \
    SB0; \
    asm volatile("s_waitcnt lgkmcnt(0)" ::: "memory"); \
    SB0; \
    __builtin_amdgcn_s_barrier(); \
    SB0; \
    if (DOSTAGE) STAGE_Y(u, ((j) + 4) * 32); \
    _Pragma("unroll") \
    for (int mi = 0; mi < 4; ++mi) \
        _Pragma("unroll") \
        for (int ni = 0; ni < 4; ++ni) \
            acc[mi][ni] = __builtin_amdgcn_mfma_f32_16x16x32_bf16(af[mi], bf[ni], acc[mi][ni], 0, 0, 0); \
} while (0)

    STAGE_Y(0, 0);
    STAGE_Y(1, 32);
    STAGE_Y(2, 64);
    STAGE_Y(3, 96);

    for (int g = 0; g < 15; ++g) {
        const int j = g * 4;
        YSTEP(0, j + 0, 12, true);
        YSTEP(1, j + 1, 12, true);
        YSTEP(2, j + 2, 12, true);
        YSTEP(3, j + 3, 12, true);
    }
    YSTEP(0, 60, 12, false);
    YSTEP(1, 61, 8, false);
    YSTEP(2, 62, 4, false);
    YSTEP(3, 63, 0, false);
#undef YSTEP
#undef STAGE_Y

#pragma unroll
    for (int mi = 0; mi < 4; ++mi) {
#pragma unroll
        for (int reg = 0; reg < 4; ++reg) {
            int m = m0 + wm * 64 + mi * 16 + quad * 4 + reg;
            if (m < cnt) {
                int entry = list[e * TT + m];
                float* yrow = Y + (size_t)entry * DD + n0 + wn * 64;
#pragma unroll
                for (int ni = 0; ni < 4; ++ni)
                    yrow[ni * 16 + lr] = acc[mi][ni][reg];
            }
        }
    }
}

// combine: out[t] = Y[2t] + Y[2t+1]   (every entry row is written exactly once)
__global__ __launch_bounds__(256) void combine_kernel(
    const float* __restrict__ Y, float* __restrict__ out)
{
    long long i4 = ((long long)blockIdx.x * 256 + threadIdx.x) * 4;
    int t = (int)(i4 >> 11);
    int d = (int)(i4 & 2047);
    float4 a = *(const float4*)(Y + (size_t)(2 * t) * DD + d);
    float4 b = *(const float4*)(Y + (size_t)(2 * t + 1) * DD + d);
    float4 r = make_float4(a.x + b.x, a.y + b.y, a.z + b.z, a.w + b.w);
    *(float4*)(out + i4) = r;
}

// ======== fallback path (round-1 kernels, fused fp32->bf16 staging) =========
__global__ __launch_bounds__(256) void gemm_h_fb(
    const float* __restrict__ x, const float* __restrict__ w1,
    const float* __restrict__ w3, const int* __restrict__ counts,
    const int* __restrict__ list, const float* __restrict__ wlist,
    __hip_bfloat16* __restrict__ H)
{
    const int e = blockIdx.z;
    const int cnt = counts[e];
    const int m0 = blockIdx.y * 128;
    if (m0 >= cnt) return;
    const int n0 = blockIdx.x * 64;
    const int tid = threadIdx.x;

    __shared__ u16 As[128][40];
    __shared__ u16 W1s[64][40];
    __shared__ u16 W3s[64][40];

    const int arow = tid >> 1;
    const int ahalf = tid & 1;
    const bool avalid = (m0 + arow) < cnt;
    const float* aptr = nullptr;
    if (avalid) {
        int entry = list[e * TT + m0 + arow];
        aptr = x + (size_t)(entry >> 1) * DD + ahalf * 16;
    }
    const int wrow = tid >> 2;
    const int wq = tid & 3;
    const float* w1ptr = w1 + ((size_t)e * II + (n0 + wrow)) * DD + wq * 8;
    const float* w3ptr = w3 + ((size_t)e * II + (n0 + wrow)) * DD + wq * 8;

    const int lane = tid & 63;
    const int wid = tid >> 6;
    const int wm = wid >> 1;
    const int wn = wid & 1;
    const int lr = lane & 15;
    const int quad = lane >> 4;

    f32x4 accA[4][2], accB[4][2];
#pragma unroll
    for (int mi = 0; mi < 4; ++mi)
#pragma unroll
        for (int ni = 0; ni < 2; ++ni) {
            accA[mi][ni] = (f32x4)0.f;
            accB[mi][ni] = (f32x4)0.f;
        }

    for (int kk = 0; kk < DD; kk += 32) {
#pragma unroll
        for (int it = 0; it < 4; ++it) {
            float4 v = make_float4(0.f, 0.f, 0.f, 0.f);
            if (avalid) v = *(const float4*)(aptr + kk + it * 4);
            st_bf4(&As[arow][ahalf * 16 + it * 4], v);
        }
#pragma unroll
        for (int it = 0; it < 2; ++it) {
            float4 v1 = *(const float4*)(w1ptr + kk + it * 4);
            st_bf4(&W1s[wrow][wq * 8 + it * 4], v1);
            float4 v3 = *(const float4*)(w3ptr + kk + it * 4);
            st_bf4(&W3s[wrow][wq * 8 + it * 4], v3);
        }
        __syncthreads();

        short8 af[4], b1f[2], b3f[2];
#pragma unroll
        for (int mi = 0; mi < 4; ++mi)
            af[mi] = *(const short8*)&As[wm * 64 + mi * 16 + lr][quad * 8];
#pragma unroll
        for (int ni = 0; ni < 2; ++ni) {
            b1f[ni] = *(const short8*)&W1s[wn * 32 + ni * 16 + lr][quad * 8];
            b3f[ni] = *(const short8*)&W3s[wn * 32 + ni * 16 + lr][quad * 8];
        }
#pragma unroll
        for (int mi = 0; mi < 4; ++mi)
#pragma unroll
            for (int ni = 0; ni < 2; ++ni) {
                accA[mi][ni] = __builtin_amdgcn_mfma_f32_16x16x32_bf16(af[mi], b1f[ni], accA[mi][ni], 0, 0, 0);
                accB[mi][ni] = __builtin_amdgcn_mfma_f32_16x16x32_bf16(af[mi], b3f[ni], accB[mi][ni], 0, 0, 0);
            }
        __syncthreads();
    }

#pragma unroll
    for (int mi = 0; mi < 4; ++mi) {
#pragma unroll
        for (int reg = 0; reg < 4; ++reg) {
            int m = m0 + wm * 64 + mi * 16 + quad * 4 + reg;
            if (m < cnt) {
                int entry = list[e * TT + m];
                float cw = wlist[e * TT + m];
                size_t hbase = (size_t)entry * II;
#pragma unroll
                for (int ni = 0; ni < 2; ++ni) {
                    int col = n0 + wn * 32 + ni * 16 + lr;
                    float a = accA[mi][ni][reg];
                    float b = accB[mi][ni][reg];
                    float g = 0.5f * a * (1.0f + erff(a * 0.70710678118654752f));
                    H[hbase + col] = __float2bfloat16(g * b * cw);
                }
            }
        }
    }
}

__global__ __launch_bounds__(256) void gemm_y_fb(
    const __hip_bfloat16* __restrict__ H, const float* __restrict__ w2,
    const int* __restrict__ counts, const int* __restrict__ list,
    float* __restrict__ out)
{
    const int e = blockIdx.z;
    const int cnt = counts[e];
    const int m0 = blockIdx.y * 128;
    if (m0 >= cnt) return;
    const int n0 = blockIdx.x * 128;
    const int tid = threadIdx.x;

    __shared__ u16 As[128][40];
    __shared__ u16 Ws[128][40];

    const int arow = tid >> 1;
    const int ahalf = tid & 1;
    const bool avalid = (m0 + arow) < cnt;
    const u16* aptr = nullptr;
    if (avalid) {
        int entry = list[e * TT + m0 + arow];
        aptr = (const u16*)H + (size_t)entry * II + ahalf * 16;
    }
    const int wrow = tid >> 1;
    const int whalf = tid & 1;
    const float* wptr = w2 + ((size_t)e * DD + (n0 + wrow)) * II + whalf * 16;

    const int lane = tid & 63;
    const int wid = tid >> 6;
    const int wm = wid >> 1;
    const int wn = wid & 1;
    const int lr = lane & 15;
    const int quad = lane >> 4;

    f32x4 acc[4][4];
#pragma unroll
    for (int mi = 0; mi < 4; ++mi)
#pragma unroll
        for (int ni = 0; ni < 4; ++ni) acc[mi][ni] = (f32x4)0.f;

    for (int kk = 0; kk < II; kk += 32) {
#pragma unroll
        for (int it = 0; it < 2; ++it) {
            int4 v = make_int4(0, 0, 0, 0);
            if (avalid) v = *(const int4*)(aptr + kk + it * 8);
            *(int4*)&As[arow][ahalf * 16 + it * 8] = v;
        }
#pragma unroll
        for (int it = 0; it < 4; ++it) {
            float4 v = *(const float4*)(wptr + kk + it * 4);
            st_bf4(&Ws[wrow][whalf * 16 + it * 4], v);
        }
        __syncthreads();

        short8 af[4], bf[4];
#pragma unroll
        for (int mi = 0; mi < 4; ++mi)
            af[mi] = *(const short8*)&As[wm * 64 + mi * 16 + lr][quad * 8];
#pragma unroll
        for (int ni = 0; ni < 4; ++ni)
            bf[ni] = *(const short8*)&Ws[wn * 64 + ni * 16 + lr][quad * 8];
#pragma unroll
        for (int mi = 0; mi < 4; ++mi)
#pragma unroll
            for (int ni = 0; ni < 4; ++ni)
                acc[mi][ni] = __builtin_amdgcn_mfma_f32_16x16x32_bf16(af[mi], bf[ni], acc[mi][ni], 0, 0, 0);
        __syncthreads();
    }

#pragma unroll
    for (int mi = 0; mi < 4; ++mi) {
#pragma unroll
        for (int reg = 0; reg < 4; ++reg) {
            int m = m0 + wm * 64 + mi * 16 + quad * 4 + reg;
            if (m < cnt) {
                int token = list[e * TT + m] >> 1;
                float* orow = out + (size_t)token * DD + n0 + wn * 64;
#pragma unroll
                for (int ni = 0; ni < 4; ++ni)
                    atomicAdd(&orow[ni * 16 + lr], acc[mi][ni][reg]);
            }
        }
    }
}

extern "C" void kernel_launch(void* const* d_in, const int* in_sizes, int n_in,
                              void* d_out, int out_size, void* d_ws, size_t ws_size,
                              hipStream_t stream) {
    const float* x  = (const float*)d_in[0];
    const float* wg = (const float*)d_in[1];
    const float* w1 = (const float*)d_in[2];
    const float* w3 = (const float*)d_in[3];
    const float* w2 = (const float*)d_in[4];
    float* out = (float*)d_out;

    char* ws = (char*)d_ws;
    int*   counts = (int*)(ws);
    int*   list   = (int*)(ws + 4096);
    float* wlist  = (float*)(ws + 4096 + 65536);
    u16*   H      = (u16*)(ws + 135168);                       // 4096 x 2048 bf16 = 16 MB
    const size_t NW = (size_t)EE * II * DD;                    // 33.55M elems per weight
    u16*   xb  = (u16*)(ws + 135168 + 16777216);               // 8 MB
    u16*   w1b = (u16*)((char*)xb + (size_t)TT * DD * 2);
    u16*   w3b = (u16*)((char*)w1b + NW * 2);
    u16*   w2b = (u16*)((char*)w3b + NW * 2);
    // Y [4096][2048] f32 = 33.5 MB aliases xb + head of w1b: xb and w1b are
    // dead after gemm_h; Y is written by gemm_y / read by combine (both
    // strictly after gemm_h in stream order).
    float* Y = (float*)xb;
    const size_t NEED = (size_t)135168 + 16777216 + (size_t)TT * DD * 2 + 3 * NW * 2;

    hipMemsetAsync(counts, 0, EE * sizeof(int), stream);

    if (ws_size >= NEED) {
        router2_kernel<<<TT / 4, 256, 0, stream>>>(x, wg, counts, list, wlist, xb);
        const int cvb = (int)(NW / 8 / 256);   // 16384 blocks per weight
        cvt3_kernel<<<dim3(cvb, 3), 256, 0, stream>>>(w1, w3, w2, w1b, w3b, w2b, (long long)NW);
        gemm_h_bf16<<<dim3(II / 64, TT / 128, EE), 256, 0, stream>>>(
            xb, w1b, w3b, counts, list, wlist, H);
        gemm_y_bf16<<<dim3(DD / 128, TT / 128, EE), 256, 0, stream>>>(
            H, w2b, counts, list, Y);
        combine_kernel<<<(TT * DD / 4) / 256, 256, 0, stream>>>(Y, out);
    } else {
        hipMemsetAsync(out, 0, (size_t)out_size * sizeof(float), stream);
        router2_kernel<<<TT / 4, 256, 0, stream>>>(x, wg, counts, list, wlist, nullptr);
        gemm_h_fb<<<dim3(II / 64, TT / 128, EE), 256, 0, stream>>>(
            x, w1, w3, counts, list, wlist, (__hip_bfloat16*)H);
        gemm_y_fb<<<dim3(DD / 128, TT / 128, EE), 256, 0, stream>>>(
            (const __hip_bfloat16*)H, w2, counts, list, out);
    }
}

// Round 4
// 610.328 us; speedup vs baseline: 1.1214x; 1.1214x over previous
//
#include <hip/hip_runtime.h>
#include <hip/hip_bf16.h>
#include <math.h>

#define TT 2048
#define DD 2048
#define EE 8
#define II 2048
#define SOFTCAP 30.0f

typedef __attribute__((ext_vector_type(8))) short short8;
typedef __attribute__((ext_vector_type(4))) float f32x4;
typedef unsigned short u16;

__device__ __forceinline__ u16 f2bs(float f) {
    union { __hip_bfloat16 h; u16 u; } cv;
    cv.h = __float2bfloat16(f);
    return cv.u;
}

__device__ __forceinline__ void st_bf4(u16* p, float4 v) {
    unsigned int lo = (unsigned int)f2bs(v.x) | ((unsigned int)f2bs(v.y) << 16);
    unsigned int hi = (unsigned int)f2bs(v.z) | ((unsigned int)f2bs(v.w) << 16);
    *(uint2*)p = make_uint2(lo, hi);
}

// non-temporal 16B load/store via native clang vector type (HIP float4 is a
// wrapped class and is rejected by the builtin — round-3 compile error).
__device__ __forceinline__ float4 ntld4(const float* p) {
    f32x4 v = __builtin_nontemporal_load((const f32x4*)p);
    return make_float4(v.x, v.y, v.z, v.w);
}
__device__ __forceinline__ void ntst4(float* p, float4 v) {
    f32x4 t = {v.x, v.y, v.z, v.w};
    __builtin_nontemporal_store(t, (f32x4*)p);
}

__device__ __forceinline__ void gload16(const void* g, void* l) {
    __builtin_amdgcn_global_load_lds(
        (const __attribute__((address_space(1))) unsigned int*)g,
        (__attribute__((address_space(3))) unsigned int*)l,
        16, 0, 0);
}

// ---------------- fp32 -> bf16 bulk convert, all 3 weights in one launch ----
// fp32 SOURCE reads are non-temporal (nt) so they do not allocate in the
// 256 MB L3 — then the allocating traffic is only the 201 MB of bf16 writes
// (+16 MB xb), and w1b/w3b are L3-RESIDENT when gemm_h starts (round-2
// post-mortem: cached fp32 reads evicted them -> 126 MB HBM re-fetch).
// Order: w2 first, w1/w3 last (freshest).
__global__ __launch_bounds__(256) void cvt3_kernel(
    const float* __restrict__ w1, const float* __restrict__ w3,
    const float* __restrict__ w2, u16* __restrict__ d1, u16* __restrict__ d3,
    u16* __restrict__ d2, long long n)
{
    const float* s;
    u16* d;
    if (blockIdx.y == 0)      { s = w2; d = d2; }
    else if (blockIdx.y == 1) { s = w1; d = d1; }
    else                      { s = w3; d = d3; }
    long long i = ((long long)blockIdx.x * 256 + threadIdx.x) * 8;
    if (i >= n) return;
    float4 a = ntld4(s + i);
    float4 b = ntld4(s + i + 4);
    st_bf4(d + i, a);
    st_bf4(d + i + 4, b);
}

// ---------------- router: wave per token; also emits x in bf16 --------------
__global__ __launch_bounds__(256) void router2_kernel(
    const float* __restrict__ x, const float* __restrict__ wg,
    int* __restrict__ counts, int* __restrict__ list, float* __restrict__ wlist,
    u16* __restrict__ xb)
{
    const int wid = threadIdx.x >> 6;
    const int lane = threadIdx.x & 63;
    const int t = blockIdx.x * 4 + wid;
    const float* xr = x + (size_t)t * DD;
    float acc[EE];
#pragma unroll
    for (int e = 0; e < EE; ++e) acc[e] = 0.f;
    for (int i = 0; i < DD; i += 256) {
        float4 xv = ntld4(xr + i + lane * 4);   // x read once -> nt
        if (xb) st_bf4(xb + (size_t)t * DD + i + lane * 4, xv);
#pragma unroll
        for (int e = 0; e < EE; ++e) {
            float4 wv = *(const float4*)(wg + (size_t)e * DD + i + lane * 4);
            acc[e] += xv.x * wv.x + xv.y * wv.y + xv.z * wv.z + xv.w * wv.w;
        }
    }
#pragma unroll
    for (int e = 0; e < EE; ++e) {
#pragma unroll
        for (int off = 32; off > 0; off >>= 1)
            acc[e] += __shfl_xor(acc[e], off, 64);
    }
    if (lane == 0) {
        float p[EE];
        float mx = -1e30f;
#pragma unroll
        for (int e = 0; e < EE; ++e) {
            p[e] = SOFTCAP * tanhf(acc[e] / SOFTCAP);
            mx = fmaxf(mx, p[e]);
        }
        float s = 0.f;
#pragma unroll
        for (int e = 0; e < EE; ++e) { p[e] = expf(p[e] - mx); s += p[e]; }
        float inv = 1.f / s;
        int i0 = 0;
#pragma unroll
        for (int e = 1; e < EE; ++e) if (p[e] > p[i0]) i0 = e;
        int i1 = (i0 == 0) ? 1 : 0;
#pragma unroll
        for (int e = 0; e < EE; ++e) if (e != i0 && p[e] > p[i1]) i1 = e;
        int pos0 = atomicAdd(&counts[i0], 1);
        list[i0 * TT + pos0] = t * 2;
        wlist[i0 * TT + pos0] = p[i0] * inv;
        int pos1 = atomicAdd(&counts[i1], 1);
        list[i1 * TT + pos1] = t * 2 + 1;
        wlist[i1 * TT + pos1] = p[i1] * inv;
    }
}

// ======== bf16 fast path =====================================================
// LDS swizzle: slot (row,s) holds data col s^((row>>1)&3); per-lane GLOBAL
// source col pre-swizzled (gload_lds writes linearly), ds_read applies the
// same XOR.  Bank conflicts: 0 (verified rounds 1-2).
//
// Pipeline: depth-2 counted vmcnt at 32 KB LDS (round-2 lesson: 64 KB depth-4
// cut occupancy 25->18% and lost more than the pipeline gained; grid supplies
// ~4 blocks/CU and cross-block TLP is the main latency hider).  Per step j
// (buffer u = j&1):
//   vmcnt(4)   -> my tile-j loads landed (tile j+1 stays in flight)
//   s_barrier  -> everyone's tile-j loads landed
//   ds_read tile j ; lgkmcnt(0)
//   s_barrier  -> everyone done reading buffer u; safe to overwrite
//   STAGE tile j+2 into buffer u ; MFMA on tile j
// Lead time = 2 periods (~1000 cy) > L3 hit latency (~300 cy).

#define SB0 __builtin_amdgcn_sched_barrier(0)

// phase A: h = gelu(x@w1^T)*(x@w3^T)*cw ; tile 128M x 64N x 32K, dual-matrix
__global__ __launch_bounds__(256) void gemm_h_bf16(
    const u16* __restrict__ xb, const u16* __restrict__ w1b,
    const u16* __restrict__ w3b, const int* __restrict__ counts,
    const int* __restrict__ list, const float* __restrict__ wlist,
    u16* __restrict__ H)
{
    const int e = blockIdx.z;
    const int cnt = counts[e];
    const int m0 = blockIdx.y * 128;
    if (m0 >= cnt) return;
    const int n0 = blockIdx.x * 64;
    const int tid = threadIdx.x;
    const int lane = tid & 63;
    const int w = tid >> 6;

    __shared__ u16 As[2][128 * 32];
    __shared__ u16 W1s[2][64 * 32];
    __shared__ u16 W3s[2][64 * 32];

    const int colb = ((lane & 3) ^ ((lane >> 3) & 3)) * 8;  // pre-swizzled src col
    const int rsub = lane >> 2;
    const int rA0 = w * 16 + rsub;
    const int rA1 = 64 + rA0;
    const int mA0 = m0 + rA0, mA1 = m0 + rA1;
    const int t0 = (mA0 < cnt) ? (list[e * TT + mA0] >> 1) : 0;
    const int t1 = (mA1 < cnt) ? (list[e * TT + mA1] >> 1) : 0;
    const u16* gA0 = xb + (size_t)t0 * DD + colb;
    const u16* gA1 = xb + (size_t)t1 * DD + colb;
    const int rW = w * 16 + rsub;
    const u16* gW1 = w1b + ((size_t)e * II + n0 + rW) * DD + colb;
    const u16* gW3 = w3b + ((size_t)e * II + n0 + rW) * DD + colb;

    const int wm = w >> 1, wn = w & 1;
    const int lr = lane & 15;
    const int quad = lane >> 4;
    const int qc = (quad ^ ((lr >> 1) & 3)) * 8;  // swizzled read col (u16 units)

    f32x4 accA[4][2], accB[4][2];
#pragma unroll
    for (int mi = 0; mi < 4; ++mi)
#pragma unroll
        for (int ni = 0; ni < 2; ++ni) {
            accA[mi][ni] = (f32x4)0.f;
            accB[mi][ni] = (f32x4)0.f;
        }

#define STAGE_H(u, kk) do { \
    gload16(gA0 + (kk), &As[u][(w * 16) * 32]); \
    gload16(gA1 + (kk), &As[u][(64 + w * 16) * 32]); \
    gload16(gW1 + (kk), &W1s[u][(w * 16) * 32]); \
    gload16(gW3 + (kk), &W3s[u][(w * 16) * 32]); \
} while (0)

#define HSTEP(u, j, VM, DOSTAGE) do { \
    asm volatile("s_waitcnt vmcnt(" #VM ")" ::: "memory"); \
    SB0; \
    __builtin_amdgcn_s_barrier(); \
    SB0; \
    short8 af[4], b1f[2], b3f[2]; \
    _Pragma("unroll") \
    for (int mi = 0; mi < 4; ++mi) \
        af[mi] = *(const short8*)&As[u][(wm * 64 + mi * 16 + lr) * 32 + qc]; \
    _Pragma("unroll") \
    for (int ni = 0; ni < 2; ++ni) { \
        b1f[ni] = *(const short8*)&W1s[u][(wn * 32 + ni * 16 + lr) * 32 + qc]; \
        b3f[ni] = *(const short8*)&W3s[u][(wn * 32 + ni * 16 + lr) * 32 + qc]; \
    } \
    SB0; \
    asm volatile("s_waitcnt lgkmcnt(0)" ::: "memory"); \
    SB0; \
    __builtin_amdgcn_s_barrier(); \
    SB0; \
    if (DOSTAGE) STAGE_H(u, ((j) + 2) * 32); \
    _Pragma("unroll") \
    for (int mi = 0; mi < 4; ++mi) \
        _Pragma("unroll") \
        for (int ni = 0; ni < 2; ++ni) { \
            accA[mi][ni] = __builtin_amdgcn_mfma_f32_16x16x32_bf16(af[mi], b1f[ni], accA[mi][ni], 0, 0, 0); \
            accB[mi][ni] = __builtin_amdgcn_mfma_f32_16x16x32_bf16(af[mi], b3f[ni], accB[mi][ni], 0, 0, 0); \
        } \
} while (0)

    STAGE_H(0, 0);
    STAGE_H(1, 32);

    for (int g = 0; g < 31; ++g) {
        const int j = g * 2;
        HSTEP(0, j + 0, 4, true);
        HSTEP(1, j + 1, 4, true);
    }
    HSTEP(0, 62, 4, false);
    HSTEP(1, 63, 0, false);
#undef HSTEP
#undef STAGE_H

#pragma unroll
    for (int mi = 0; mi < 4; ++mi) {
#pragma unroll
        for (int reg = 0; reg < 4; ++reg) {
            int m = m0 + wm * 64 + mi * 16 + quad * 4 + reg;
            if (m < cnt) {
                int entry = list[e * TT + m];
                float cw = wlist[e * TT + m];
                size_t hbase = (size_t)entry * II;
#pragma unroll
                for (int ni = 0; ni < 2; ++ni) {
                    int col = n0 + wn * 32 + ni * 16 + lr;
                    float a = accA[mi][ni][reg];
                    float b = accB[mi][ni][reg];
                    float g2 = 0.5f * a * (1.0f + erff(a * 0.70710678118654752f));
                    H[hbase + col] = f2bs(g2 * b * cw);
                }
            }
        }
    }
}

// phase B: Y[entry] = H[entry] @ w2^T, plain stores (no atomics); 128x128x32
__global__ __launch_bounds__(256) void gemm_y_bf16(
    const u16* __restrict__ H, const u16* __restrict__ w2b,
    const int* __restrict__ counts, const int* __restrict__ list,
    float* __restrict__ Y)
{
    const int e = blockIdx.z;
    const int cnt = counts[e];
    const int m0 = blockIdx.y * 128;
    if (m0 >= cnt) return;
    const int n0 = blockIdx.x * 128;
    const int tid = threadIdx.x;
    const int lane = tid & 63;
    const int w = tid >> 6;

    __shared__ u16 As[2][128 * 32];
    __shared__ u16 Bs[2][128 * 32];

    const int colb = ((lane & 3) ^ ((lane >> 3) & 3)) * 8;
    const int rsub = lane >> 2;
    const int rA0 = w * 16 + rsub;
    const int rA1 = 64 + rA0;
    const int eA0 = (m0 + rA0 < cnt) ? list[e * TT + m0 + rA0] : 0;
    const int eA1 = (m0 + rA1 < cnt) ? list[e * TT + m0 + rA1] : 0;
    const u16* gA0 = H + (size_t)eA0 * II + colb;
    const u16* gA1 = H + (size_t)eA1 * II + colb;
    const u16* gB0 = w2b + ((size_t)e * DD + n0 + rA0) * II + colb;
    const u16* gB1 = w2b + ((size_t)e * DD + n0 + rA1) * II + colb;

    const int wm = w >> 1, wn = w & 1;
    const int lr = lane & 15;
    const int quad = lane >> 4;
    const int qc = (quad ^ ((lr >> 1) & 3)) * 8;

    f32x4 acc[4][4];
#pragma unroll
    for (int mi = 0; mi < 4; ++mi)
#pragma unroll
        for (int ni = 0; ni < 4; ++ni) acc[mi][ni] = (f32x4)0.f;

#define STAGE_Y(u, kk) do { \
    gload16(gA0 + (kk), &As[u][(w * 16) * 32]); \
    gload16(gA1 + (kk), &As[u][(64 + w * 16) * 32]); \
    gload16(gB0 + (kk), &Bs[u][(w * 16) * 32]); \
    gload16(gB1 + (kk), &Bs[u][(64 + w * 16) * 32]); \
} while (0)

#define YSTEP(u, j, VM, DOSTAGE) do { \
    asm volatile("s_waitcnt vmcnt(" #VM ")" ::: "memory"); \
    SB0; \
    __builtin_amdgcn_s_barrier(); \
    SB0; \
    short8 af[4], bf[4]; \
    _Pragma("unroll") \
    for (int mi = 0; mi < 4; ++mi) \
        af[mi] = *(const short8*)&As[u][(wm * 64 + mi * 16 + lr) * 32 + qc]; \
    _Pragma("unroll") \
    for (int ni = 0; ni < 4; ++ni) \
        bf[ni] = *(const short8*)&Bs[u][(wn * 64 + ni * 16 + lr) * 32 + qc]; \
    SB0; \
    asm volatile("s_waitcnt lgkmcnt(0)" ::: "memory"); \
    SB0; \
    __builtin_amdgcn_s_barrier(); \
    SB0; \
    if (DOSTAGE) STAGE_Y(u, ((j) + 2) * 32); \
    _Pragma("unroll") \
    for (int mi = 0; mi < 4; ++mi) \
        _Pragma("unroll") \
        for (int ni = 0; ni < 4; ++ni) \
            acc[mi][ni] = __builtin_amdgcn_mfma_f32_16x16x32_bf16(af[mi], bf[ni], acc[mi][ni], 0, 0, 0); \
} while (0)

    STAGE_Y(0, 0);
    STAGE_Y(1, 32);

    for (int g = 0; g < 31; ++g) {
        const int j = g * 2;
        YSTEP(0, j + 0, 4, true);
        YSTEP(1, j + 1, 4, true);
    }
    YSTEP(0, 62, 4, false);
    YSTEP(1, 63, 0, false);
#undef YSTEP
#undef STAGE_Y

#pragma unroll
    for (int mi = 0; mi < 4; ++mi) {
#pragma unroll
        for (int reg = 0; reg < 4; ++reg) {
            int m = m0 + wm * 64 + mi * 16 + quad * 4 + reg;
            if (m < cnt) {
                int entry = list[e * TT + m];
                float* yrow = Y + (size_t)entry * DD + n0 + wn * 64;
#pragma unroll
                for (int ni = 0; ni < 4; ++ni)
                    yrow[ni * 16 + lr] = acc[mi][ni][reg];
            }
        }
    }
}

// combine: out[t] = Y[2t] + Y[2t+1]   (every entry row is written exactly once)
__global__ __launch_bounds__(256) void combine_kernel(
    const float* __restrict__ Y, float* __restrict__ out)
{
    long long i4 = ((long long)blockIdx.x * 256 + threadIdx.x) * 4;
    int t = (int)(i4 >> 11);
    int d = (int)(i4 & 2047);
    float4 a = *(const float4*)(Y + (size_t)(2 * t) * DD + d);
    float4 b = *(const float4*)(Y + (size_t)(2 * t + 1) * DD + d);
    float4 r = make_float4(a.x + b.x, a.y + b.y, a.z + b.z, a.w + b.w);
    ntst4(out + i4, r);  // out never re-read on device
}

// ======== fallback path (round-1 kernels, fused fp32->bf16 staging) =========
__global__ __launch_bounds__(256) void gemm_h_fb(
    const float* __restrict__ x, const float* __restrict__ w1,
    const float* __restrict__ w3, const int* __restrict__ counts,
    const int* __restrict__ list, const float* __restrict__ wlist,
    __hip_bfloat16* __restrict__ H)
{
    const int e = blockIdx.z;
    const int cnt = counts[e];
    const int m0 = blockIdx.y * 128;
    if (m0 >= cnt) return;
    const int n0 = blockIdx.x * 64;
    const int tid = threadIdx.x;

    __shared__ u16 As[128][40];
    __shared__ u16 W1s[64][40];
    __shared__ u16 W3s[64][40];

    const int arow = tid >> 1;
    const int ahalf = tid & 1;
    const bool avalid = (m0 + arow) < cnt;
    const float* aptr = nullptr;
    if (avalid) {
        int entry = list[e * TT + m0 + arow];
        aptr = x + (size_t)(entry >> 1) * DD + ahalf * 16;
    }
    const int wrow = tid >> 2;
    const int wq = tid & 3;
    const float* w1ptr = w1 + ((size_t)e * II + (n0 + wrow)) * DD + wq * 8;
    const float* w3ptr = w3 + ((size_t)e * II + (n0 + wrow)) * DD + wq * 8;

    const int lane = tid & 63;
    const int wid = tid >> 6;
    const int wm = wid >> 1;
    const int wn = wid & 1;
    const int lr = lane & 15;
    const int quad = lane >> 4;

    f32x4 accA[4][2], accB[4][2];
#pragma unroll
    for (int mi = 0; mi < 4; ++mi)
#pragma unroll
        for (int ni = 0; ni < 2; ++ni) {
            accA[mi][ni] = (f32x4)0.f;
            accB[mi][ni] = (f32x4)0.f;
        }

    for (int kk = 0; kk < DD; kk += 32) {
#pragma unroll
        for (int it = 0; it < 4; ++it) {
            float4 v = make_float4(0.f, 0.f, 0.f, 0.f);
            if (avalid) v = *(const float4*)(aptr + kk + it * 4);
            st_bf4(&As[arow][ahalf * 16 + it * 4], v);
        }
#pragma unroll
        for (int it = 0; it < 2; ++it) {
            float4 v1 = *(const float4*)(w1ptr + kk + it * 4);
            st_bf4(&W1s[wrow][wq * 8 + it * 4], v1);
            float4 v3 = *(const float4*)(w3ptr + kk + it * 4);
            st_bf4(&W3s[wrow][wq * 8 + it * 4], v3);
        }
        __syncthreads();

        short8 af[4], b1f[2], b3f[2];
#pragma unroll
        for (int mi = 0; mi < 4; ++mi)
            af[mi] = *(const short8*)&As[wm * 64 + mi * 16 + lr][quad * 8];
#pragma unroll
        for (int ni = 0; ni < 2; ++ni) {
            b1f[ni] = *(const short8*)&W1s[wn * 32 + ni * 16 + lr][quad * 8];
            b3f[ni] = *(const short8*)&W3s[wn * 32 + ni * 16 + lr][quad * 8];
        }
#pragma unroll
        for (int mi = 0; mi < 4; ++mi)
#pragma unroll
            for (int ni = 0; ni < 2; ++ni) {
                accA[mi][ni] = __builtin_amdgcn_mfma_f32_16x16x32_bf16(af[mi], b1f[ni], accA[mi][ni], 0, 0, 0);
                accB[mi][ni] = __builtin_amdgcn_mfma_f32_16x16x32_bf16(af[mi], b3f[ni], accB[mi][ni], 0, 0, 0);
            }
        __syncthreads();
    }

#pragma unroll
    for (int mi = 0; mi < 4; ++mi) {
#pragma unroll
        for (int reg = 0; reg < 4; ++reg) {
            int m = m0 + wm * 64 + mi * 16 + quad * 4 + reg;
            if (m < cnt) {
                int entry = list[e * TT + m];
                float cw = wlist[e * TT + m];
                size_t hbase = (size_t)entry * II;
#pragma unroll
                for (int ni = 0; ni < 2; ++ni) {
                    int col = n0 + wn * 32 + ni * 16 + lr;
                    float a = accA[mi][ni][reg];
                    float b = accB[mi][ni][reg];
                    float g = 0.5f * a * (1.0f + erff(a * 0.70710678118654752f));
                    H[hbase + col] = __float2bfloat16(g * b * cw);
                }
            }
        }
    }
}

__global__ __launch_bounds__(256) void gemm_y_fb(
    const __hip_bfloat16* __restrict__ H, const float* __restrict__ w2,
    const int* __restrict__ counts, const int* __restrict__ list,
    float* __restrict__ out)
{
    const int e = blockIdx.z;
    const int cnt = counts[e];
    const int m0 = blockIdx.y * 128;
    if (m0 >= cnt) return;
    const int n0 = blockIdx.x * 128;
    const int tid = threadIdx.x;

    __shared__ u16 As[128][40];
    __shared__ u16 Ws[128][40];

    const int arow = tid >> 1;
    const int ahalf = tid & 1;
    const bool avalid = (m0 + arow) < cnt;
    const u16* aptr = nullptr;
    if (avalid) {
        int entry = list[e * TT + m0 + arow];
        aptr = (const u16*)H + (size_t)entry * II + ahalf * 16;
    }
    const int wrow = tid >> 1;
    const int whalf = tid & 1;
    const float* wptr = w2 + ((size_t)e * DD + (n0 + wrow)) * II + whalf * 16;

    const int lane = tid & 63;
    const int wid = tid >> 6;
    const int wm = wid >> 1;
    const int wn = wid & 1;
    const int lr = lane & 15;
    const int quad = lane >> 4;

    f32x4 acc[4][4];
#pragma unroll
    for (int mi = 0; mi < 4; ++mi)
#pragma unroll
        for (int ni = 0; ni < 4; ++ni) acc[mi][ni] = (f32x4)0.f;

    for (int kk = 0; kk < II; kk += 32) {
#pragma unroll
        for (int it = 0; it < 2; ++it) {
            int4 v = make_int4(0, 0, 0, 0);
            if (avalid) v = *(const int4*)(aptr + kk + it * 8);
            *(int4*)&As[arow][ahalf * 16 + it * 8] = v;
        }
#pragma unroll
        for (int it = 0; it < 4; ++it) {
            float4 v = *(const float4*)(wptr + kk + it * 4);
            st_bf4(&Ws[wrow][whalf * 16 + it * 4], v);
        }
        __syncthreads();

        short8 af[4], bf[4];
#pragma unroll
        for (int mi = 0; mi < 4; ++mi)
            af[mi] = *(const short8*)&As[wm * 64 + mi * 16 + lr][quad * 8];
#pragma unroll
        for (int ni = 0; ni < 4; ++ni)
            bf[ni] = *(const short8*)&Ws[wn * 64 + ni * 16 + lr][quad * 8];
#pragma unroll
        for (int mi = 0; mi < 4; ++mi)
#pragma unroll
            for (int ni = 0; ni < 4; ++ni)
                acc[mi][ni] = __builtin_amdgcn_mfma_f32_16x16x32_bf16(af[mi], bf[ni], acc[mi][ni], 0, 0, 0);
        __syncthreads();
    }

#pragma unroll
    for (int mi = 0; mi < 4; ++mi) {
#pragma unroll
        for (int reg = 0; reg < 4; ++reg) {
            int m = m0 + wm * 64 + mi * 16 + quad * 4 + reg;
            if (m < cnt) {
                int token = list[e * TT + m] >> 1;
                float* orow = out + (size_t)token * DD + n0 + wn * 64;
#pragma unroll
                for (int ni = 0; ni < 4; ++ni)
                    atomicAdd(&orow[ni * 16 + lr], acc[mi][ni][reg]);
            }
        }
    }
}

extern "C" void kernel_launch(void* const* d_in, const int* in_sizes, int n_in,
                              void* d_out, int out_size, void* d_ws, size_t ws_size,
                              hipStream_t stream) {
    const float* x  = (const float*)d_in[0];
    const float* wg = (const float*)d_in[1];
    const float* w1 = (const float*)d_in[2];
    const float* w3 = (const float*)d_in[3];
    const float* w2 = (const float*)d_in[4];
    float* out = (float*)d_out;

    char* ws = (char*)d_ws;
    int*   counts = (int*)(ws);
    int*   list   = (int*)(ws + 4096);
    float* wlist  = (float*)(ws + 4096 + 65536);
    u16*   H      = (u16*)(ws + 135168);                       // 4096 x 2048 bf16 = 16 MB
    const size_t NW = (size_t)EE * II * DD;                    // 33.55M elems per weight
    u16*   xb  = (u16*)(ws + 135168 + 16777216);               // 8 MB
    u16*   w1b = (u16*)((char*)xb + (size_t)TT * DD * 2);
    u16*   w3b = (u16*)((char*)w1b + NW * 2);
    u16*   w2b = (u16*)((char*)w3b + NW * 2);
    // Y [4096][2048] f32 = 33.5 MB aliases xb + head of w1b: xb and w1b are
    // dead after gemm_h; Y is written by gemm_y / read by combine (both
    // strictly after gemm_h in stream order).
    float* Y = (float*)xb;
    const size_t NEED = (size_t)135168 + 16777216 + (size_t)TT * DD * 2 + 3 * NW * 2;

    hipMemsetAsync(counts, 0, EE * sizeof(int), stream);

    if (ws_size >= NEED) {
        router2_kernel<<<TT / 4, 256, 0, stream>>>(x, wg, counts, list, wlist, xb);
        const int cvb = (int)(NW / 8 / 256);   // 16384 blocks per weight
        cvt3_kernel<<<dim3(cvb, 3), 256, 0, stream>>>(w1, w3, w2, w1b, w3b, w2b, (long long)NW);
        gemm_h_bf16<<<dim3(II / 64, TT / 128, EE), 256, 0, stream>>>(
            xb, w1b, w3b, counts, list, wlist, H);
        gemm_y_bf16<<<dim3(DD / 128, TT / 128, EE), 256, 0, stream>>>(
            H, w2b, counts, list, Y);
        combine_kernel<<<(TT * DD / 4) / 256, 256, 0, stream>>>(Y, out);
    } else {
        hipMemsetAsync(out, 0, (size_t)out_size * sizeof(float), stream);
        router2_kernel<<<TT / 4, 256, 0, stream>>>(x, wg, counts, list, wlist, nullptr);
        gemm_h_fb<<<dim3(II / 64, TT / 128, EE), 256, 0, stream>>>(
            x, w1, w3, counts, list, wlist, (__hip_bfloat16*)H);
        gemm_y_fb<<<dim3(DD / 128, TT / 128, EE), 256, 0, stream>>>(
            (const __hip_bfloat16*)H, w2, counts, list, out);
    }
}